// Round 1
// baseline (74.116 us; speedup 1.0000x reference)
//
#include <hip/hip_runtime.h>

// Stein layer, two-kernel split. B=65536, D=32, H=128.
// prep (1 block): packs bf16 B-fragment image (25 tiles: 8 W1hi + 8 W1lo +
//   9 W2T incl. b2-augmented col) + (c_k, b1_k) pairs into workspace.
// main (1024 blocks x 256 thr, 4 waves, 16 rows/wave): barrier-free,
//   LDS-free. B-frags stream from L2 (26.6 KB working set, shared by all
//   blocks). Removes per-block re-pack (~48 KB redundant reads + ~400 VALU
//   conversion ops/thread + __syncthreads drain) from the critical path.
// out[r] = sum_k [ c_k - h_k*(h_k*c_k + v_k) ] - x.b2 + theta0
//   z = x W1 + b1 (dual-bf16 MFMA), h = tanh(z); v = x W2^T; c_k = W1[:,k].W2[k,:]

#define NROWS 65536
#define DD 32
#define HH 128
#define NTILE 25

typedef __attribute__((ext_vector_type(8))) short short8;
typedef __attribute__((ext_vector_type(4))) float f32x4;

static __device__ __forceinline__ unsigned short f2bf(float f) {
    unsigned u = __float_as_uint(f);
    u += 0x7fff + ((u >> 16) & 1);  // RNE
    return (unsigned short)(u >> 16);
}
static __device__ __forceinline__ float bf2f(unsigned short h) {
    return __uint_as_float(((unsigned)h) << 16);
}

// ---- prep: one block packs everything into ws ----
__global__ __launch_bounds__(256) void stein_prep(
    const float* __restrict__ W1, const float* __restrict__ b1,
    const float* __restrict__ W2, const float* __restrict__ b2,
    float2* __restrict__ cbw, unsigned short* __restrict__ lbw) {
    const int tid = threadIdx.x;
    if (tid < 128) {
        // W1 column n -> tiles n>>4 (hi) and 8+(n>>4) (lo), all 4 k-groups.
        const int n = tid;
        const int t = n >> 4, cc = n & 15;
#pragma unroll
        for (int kg = 0; kg < 4; ++kg) {
            short8 hi, lo;
#pragma unroll
            for (int j = 0; j < 8; ++j) {
                const float w = W1[(kg * 8 + j) * HH + n];
                const unsigned short h = f2bf(w);
                hi[j] = (short)h;
                lo[j] = (short)f2bf(w - bf2f(h));
            }
            *(short8*)(lbw + t * 512 + (kg * 16 + cc) * 8) = hi;
            *(short8*)(lbw + (8 + t) * 512 + (kg * 16 + cc) * 8) = lo;
        }
    } else {
        // W2 row n -> W2T column n (tile 16+(n>>4)); c_n + b1_n; tile 24.
        const int n = tid - 128;
        const int t2 = 16 + (n >> 4), cc = n & 15;
        float row[DD];
        const float4* wr = (const float4*)(W2 + n * DD);
#pragma unroll
        for (int q = 0; q < 8; ++q) {
            const float4 f = wr[q];
            row[4 * q + 0] = f.x; row[4 * q + 1] = f.y;
            row[4 * q + 2] = f.z; row[4 * q + 3] = f.w;
        }
#pragma unroll
        for (int g = 0; g < 4; ++g) {
            short8 v;
#pragma unroll
            for (int j = 0; j < 8; ++j) v[j] = (short)f2bf(row[g * 8 + j]);
            *(short8*)(lbw + t2 * 512 + (g * 16 + cc) * 8) = v;
        }
        float acc = 0.f;
#pragma unroll
        for (int k = 0; k < DD; ++k) acc = fmaf(W1[k * HH + n], row[k], acc);
        cbw[n] = make_float2(acc, b1[n]);
        if (n < 16) {
            // Tile 24: augmented col 128+n -> b2 (n==0) else zeros.
#pragma unroll
            for (int g = 0; g < 4; ++g) {
                short8 v;
#pragma unroll
                for (int j = 0; j < 8; ++j)
                    v[j] = (n == 0) ? (short)f2bf(b2[g * 8 + j]) : (short)0;
                *(short8*)(lbw + 24 * 512 + (g * 16 + n) * 8) = v;
            }
        }
    }
}

// ---- main: barrier-free, LDS-free row pass ----
__global__ __launch_bounds__(256, 4) void stein_main(
    const float* __restrict__ x, const float* __restrict__ theta,
    const float2* __restrict__ cbw, const unsigned short* __restrict__ lbw,
    float* __restrict__ out) {
    const int tid = threadIdx.x;
    const int lane = tid & 63;
    const int wv = tid >> 6;       // 4 waves
    const int quad = lane >> 4;
    const int cl = lane & 15;
    const int rowbase = blockIdx.x * 64 + wv * 16;

    // A[m=cl][k=quad*8+j]
    const float* xr = x + (size_t)(rowbase + cl) * DD + quad * 8;
    const float4 x0 = *(const float4*)xr;
    const float4 x1 = *(const float4*)(xr + 4);

    const float xv[8] = {x0.x, x0.y, x0.z, x0.w, x1.x, x1.y, x1.z, x1.w};
    short8 aHi, aLo;
#pragma unroll
    for (int j = 0; j < 8; ++j) {
        const unsigned short h = f2bf(xv[j]);
        aHi[j] = (short)h;
        aLo[j] = (short)f2bf(xv[j] - bf2f(h));
    }

    const f32x4 zero = {0.f, 0.f, 0.f, 0.f};
    float sa[4] = {0.f, 0.f, 0.f, 0.f};
    // Fragment addressing: tile t at lbw[t*512 + lane*8], 16B/lane -> the
    // wave's load is 1KB contiguous, fully coalesced, L2-resident.
    const unsigned short* lbl = lbw + lane * 8;

#pragma unroll
    for (int t = 0; t < 8; ++t) {
        const short8 bH = *(const short8*)(lbl + t * 512);
        const short8 bL = *(const short8*)(lbl + (8 + t) * 512);
        const short8 bW = *(const short8*)(lbl + (16 + t) * 512);
        const float2 cbv = cbw[t * 16 + cl];
        f32x4 z = zero;
        z = __builtin_amdgcn_mfma_f32_16x16x32_bf16(aLo, bH, z, 0, 0, 0);
        z = __builtin_amdgcn_mfma_f32_16x16x32_bf16(aHi, bL, z, 0, 0, 0);
        z = __builtin_amdgcn_mfma_f32_16x16x32_bf16(aHi, bH, z, 0, 0, 0);
        const f32x4 v = __builtin_amdgcn_mfma_f32_16x16x32_bf16(aHi, bW, zero, 0, 0, 0);
#pragma unroll
        for (int r = 0; r < 4; ++r) {
            const float zz = z[r] + cbv.y;
            const float e = __expf(2.f * zz);  // inf->h=1, 0->h=-1: exact
            const float h = fmaf(-2.f, __builtin_amdgcn_rcpf(e + 1.f), 1.f);
            sa[r] += cbv.x - h * fmaf(h, cbv.x, v[r]);  // c - h^2 c - h v
        }
    }
    {  // Augmented tile 24: x.b2 lands in col 128 (cl==0), others exact zero.
        const short8 bW = *(const short8*)(lbl + 24 * 512);
        const f32x4 v = __builtin_amdgcn_mfma_f32_16x16x32_bf16(aHi, bW, zero, 0, 0, 0);
#pragma unroll
        for (int r = 0; r < 4; ++r) sa[r] -= v[r];
    }

    // Reduce over the 16 output columns (cl bits of the lane id).
#pragma unroll
    for (int r = 0; r < 4; ++r) {
#pragma unroll
        for (int m = 1; m < 16; m <<= 1) sa[r] += __shfl_xor(sa[r], m, 64);
    }

    // C/D rows: row = quad*4 + reg -> lane cl==0 stores 4 consecutive rows.
    if (cl == 0) {
        const float th = theta[0];
        float4 o;
        o.x = sa[0] + th;
        o.y = sa[1] + th;
        o.z = sa[2] + th;
        o.w = sa[3] + th;
        *(float4*)(out + rowbase + quad * 4) = o;
    }
}

extern "C" void kernel_launch(void* const* d_in, const int* in_sizes, int n_in,
                              void* d_out, int out_size, void* d_ws, size_t ws_size,
                              hipStream_t stream) {
    const float* x = (const float*)d_in[0];
    const float* W1 = (const float*)d_in[1];
    const float* b1 = (const float*)d_in[2];
    const float* W2 = (const float*)d_in[3];
    const float* b2 = (const float*)d_in[4];
    const float* theta = (const float*)d_in[5];
    float* out = (float*)d_out;

    // ws layout: [0,1KB) float2 cb[128]; [1KB, 1KB+25.6KB) ushort lb[25*512].
    float2* cbw = (float2*)d_ws;
    unsigned short* lbw = (unsigned short*)((char*)d_ws + 1024);

    stein_prep<<<1, 256, 0, stream>>>(W1, b1, W2, b2, cbw, lbw);
    stein_main<<<NROWS / 64, 256, 0, stream>>>(x, theta, cbw, lbw, out);
}